// Round 8
// baseline (1693.822 us; speedup 1.0000x reference)
//
#include <hip/hip_runtime.h>
#include <math.h>

// Problem dims: B=16, C=256, H=W=128
#define BATCHES       16
#define CHANNELS      256
#define HW            (128 * 128)          // 16384 floats per channel
#define VEC_PER_BATCH (1 << 20)            // float4 per (input,batch)
#define T             256                  // threads per block
#define NB            512                  // persistent blocks: 2/CU guaranteed by
                                           // __launch_bounds__(256,2) (VGPR<=256)
#define WAVES_PER_BLK (T / 64)
#define TOTAL_WAVES   (NB * WAVES_PER_BLK) // 2048 wave-partials per (phase,input)
#define VEC_PER_BLK   (VEC_PER_BATCH / NB) // 2048 float4 per input per block
#define K4            (VEC_PER_BLK / T)    // 8 float4 per thread per input

// ws layout:
//   floats [0 .. 98304)        : partials [16][3][2048]
//   floats [98304 .. 98352)    : att      [16][3]
//   bytes  [393408 .. 393472)  : cnt[16]  (memset 0 each call)
//   bytes  [393472 .. 393536)  : flag[16] (memset 0 each call)
#define PART_FLOATS   (BATCHES * 3 * TOTAL_WAVES)   // 98304
#define ATT_FOFF      PART_FLOATS
#define CNT_BYTE_OFF  ((PART_FLOATS + BATCHES * 3) * 4)  // 393408
#define SYNC_BYTES    128

typedef float f32x4 __attribute__((ext_vector_type(4)));

__global__ __launch_bounds__(T, 2) void fusion_fused_kernel(
    const float4* __restrict__ gray,
    const float4* __restrict__ green,
    const float4* __restrict__ rgb,
    const float* __restrict__ conv_w,
    const float* __restrict__ conv_b,
    float* __restrict__ part,          // [16][3][2048]
    float* __restrict__ att,           // [16][3]
    unsigned int* __restrict__ cnt,    // [16]
    unsigned int* __restrict__ flag,   // [16]
    float4* __restrict__ out)
{
    const int blk  = blockIdx.x;
    const int t    = (int)threadIdx.x;
    const int lane = t & 63;
    const int wid  = t >> 6;

    // block = 2048 float4 = 8192 floats = half a channel -> uniform weight
    const float w    = conv_w[blk >> 1];
    const float bias = conv_b[0];

    __shared__ float red[3][WAVES_PER_BLK];   // leader-only use

    float4 Ag[K4], An[K4], Ar[K4], Bg[K4], Bn[K4], Br[K4];

    auto load_ph = [&](float4 (&g)[K4], float4 (&n)[K4], float4 (&r)[K4], int p) {
        const size_t base = (size_t)p * VEC_PER_BATCH + (size_t)blk * VEC_PER_BLK + (size_t)t;
        #pragma unroll
        for (int k = 0; k < K4; ++k) g[k] = gray [base + (size_t)(k * T)];
        #pragma unroll
        for (int k = 0; k < K4; ++k) n[k] = green[base + (size_t)(k * T)];
        #pragma unroll
        for (int k = 0; k < K4; ++k) r[k] = rgb  [base + (size_t)(k * T)];
    };

    auto do_ph = [&](float4 (&cg)[K4], float4 (&cn)[K4], float4 (&cr)[K4],
                     float4 (&ng)[K4], float4 (&nn)[K4], float4 (&nr)[K4],
                     int p, bool has_next) {
        // ---- per-thread sums (hw waits on cur loads here) ----
        float sg = 0.f, sn = 0.f, sr = 0.f;
        #pragma unroll
        for (int k = 0; k < K4; ++k) {
            sg += (cg[k].x + cg[k].y) + (cg[k].z + cg[k].w);
            sn += (cn[k].x + cn[k].y) + (cn[k].z + cn[k].w);
            sr += (cr[k].x + cr[k].y) + (cr[k].z + cr[k].w);
        }
        // ---- wave64 reduce (no LDS, no block sync) ----
        #pragma unroll
        for (int off = 32; off > 0; off >>= 1) {
            sg += __shfl_down(sg, off, 64);
            sn += __shfl_down(sn, off, 64);
            sr += __shfl_down(sr, off, 64);
        }
        // ---- per-wave publish + count (release) ----
        float* P = part + (size_t)p * 3 * TOTAL_WAVES;
        const int wslot = blk * WAVES_PER_BLK + wid;
        if (lane == 0) {
            __hip_atomic_store(&P[0 * TOTAL_WAVES + wslot], sg * w, __ATOMIC_RELAXED, __HIP_MEMORY_SCOPE_AGENT);
            __hip_atomic_store(&P[1 * TOTAL_WAVES + wslot], sn * w, __ATOMIC_RELAXED, __HIP_MEMORY_SCOPE_AGENT);
            __hip_atomic_store(&P[2 * TOTAL_WAVES + wslot], sr * w, __ATOMIC_RELAXED, __HIP_MEMORY_SCOPE_AGENT);
            __hip_atomic_fetch_add(&cnt[p], 1u, __ATOMIC_RELEASE, __HIP_MEMORY_SCOPE_AGENT);
        }

        // ---- prefetch next phase NOW: barrier latency hides under these ----
        if (has_next) load_ph(ng, nn, nr, p + 1);

        // ---- leader (block 0) folds all wave-partials, publishes att ----
        if (blk == 0) {
            if (t == 0) {
                while (__hip_atomic_load(&cnt[p], __ATOMIC_RELAXED, __HIP_MEMORY_SCOPE_AGENT) < TOTAL_WAVES)
                    __builtin_amdgcn_s_sleep(2);
                (void)__hip_atomic_load(&cnt[p], __ATOMIC_ACQUIRE, __HIP_MEMORY_SCOPE_AGENT);
            }
            __syncthreads();
            #pragma unroll
            for (int i = 0; i < 3; ++i) {
                const float* Pi = P + (size_t)i * TOTAL_WAVES;
                float v0 = __hip_atomic_load(&Pi[t + 0 * T], __ATOMIC_RELAXED, __HIP_MEMORY_SCOPE_AGENT);
                float v1 = __hip_atomic_load(&Pi[t + 1 * T], __ATOMIC_RELAXED, __HIP_MEMORY_SCOPE_AGENT);
                float v2 = __hip_atomic_load(&Pi[t + 2 * T], __ATOMIC_RELAXED, __HIP_MEMORY_SCOPE_AGENT);
                float v3 = __hip_atomic_load(&Pi[t + 3 * T], __ATOMIC_RELAXED, __HIP_MEMORY_SCOPE_AGENT);
                float v4 = __hip_atomic_load(&Pi[t + 4 * T], __ATOMIC_RELAXED, __HIP_MEMORY_SCOPE_AGENT);
                float v5 = __hip_atomic_load(&Pi[t + 5 * T], __ATOMIC_RELAXED, __HIP_MEMORY_SCOPE_AGENT);
                float v6 = __hip_atomic_load(&Pi[t + 6 * T], __ATOMIC_RELAXED, __HIP_MEMORY_SCOPE_AGENT);
                float v7 = __hip_atomic_load(&Pi[t + 7 * T], __ATOMIC_RELAXED, __HIP_MEMORY_SCOPE_AGENT);
                float v = ((v0 + v1) + (v2 + v3)) + ((v4 + v5) + (v6 + v7));
                #pragma unroll
                for (int off = 32; off > 0; off >>= 1) v += __shfl_down(v, off, 64);
                if (lane == 0) red[i][wid] = v;
            }
            __syncthreads();
            if (t == 0) {
                #pragma unroll
                for (int i = 0; i < 3; ++i) {
                    float tot = (red[i][0] + red[i][1]) + (red[i][2] + red[i][3]);
                    float logit = tot * (1.0f / (float)HW) + bias;
                    float a = 1.0f / (1.0f + expf(-logit));
                    __hip_atomic_store(&att[p * 3 + i], a, __ATOMIC_RELAXED, __HIP_MEMORY_SCOPE_AGENT);
                }
                __hip_atomic_store(&flag[p], 1u, __ATOMIC_RELEASE, __HIP_MEMORY_SCOPE_AGENT);
            }
        }

        // ---- every wave: spin flag, fetch att, broadcast ----
        float a0, a1, a2;
        if (lane == 0) {
            while (__hip_atomic_load(&flag[p], __ATOMIC_RELAXED, __HIP_MEMORY_SCOPE_AGENT) == 0u)
                __builtin_amdgcn_s_sleep(2);
            (void)__hip_atomic_load(&flag[p], __ATOMIC_ACQUIRE, __HIP_MEMORY_SCOPE_AGENT);
            a0 = __hip_atomic_load(&att[p * 3 + 0], __ATOMIC_RELAXED, __HIP_MEMORY_SCOPE_AGENT);
            a1 = __hip_atomic_load(&att[p * 3 + 1], __ATOMIC_RELAXED, __HIP_MEMORY_SCOPE_AGENT);
            a2 = __hip_atomic_load(&att[p * 3 + 2], __ATOMIC_RELAXED, __HIP_MEMORY_SCOPE_AGENT);
        }
        a0 = __shfl(a0, 0, 64);
        a1 = __shfl(a1, 0, 64);
        a2 = __shfl(a2, 0, 64);

        // ---- apply + nt store straight from registers ----
        const size_t base = (size_t)p * VEC_PER_BATCH + (size_t)blk * VEC_PER_BLK + (size_t)t;
        #pragma unroll
        for (int k = 0; k < K4; ++k) {
            f32x4 o;
            o.x = cg[k].x * a0 + 10.0f * (cn[k].x * a1 + cr[k].x * a2);
            o.y = cg[k].y * a0 + 10.0f * (cn[k].y * a1 + cr[k].y * a2);
            o.z = cg[k].z * a0 + 10.0f * (cn[k].z * a1 + cr[k].z * a2);
            o.w = cg[k].w * a0 + 10.0f * (cn[k].w * a1 + cr[k].w * a2);
            __builtin_nontemporal_store(o, reinterpret_cast<f32x4*>(&out[base + (size_t)(k * T)]));
        }
    };

    load_ph(Ag, An, Ar, 0);
    for (int i = 0; i < BATCHES / 2; ++i) {
        do_ph(Ag, An, Ar, Bg, Bn, Br, 2 * i, true);
        do_ph(Bg, Bn, Br, Ag, An, Ar, 2 * i + 1, (2 * i + 1) < (BATCHES - 1));
    }
}

extern "C" void kernel_launch(void* const* d_in, const int* in_sizes, int n_in,
                              void* d_out, int out_size, void* d_ws, size_t ws_size,
                              hipStream_t stream) {
    const float4* gray   = (const float4*)d_in[0];
    const float4* green  = (const float4*)d_in[1];
    const float4* rgb    = (const float4*)d_in[2];
    const float*  conv_w = (const float*)d_in[3];
    const float*  conv_b = (const float*)d_in[4];
    float4* out = (float4*)d_out;

    float*        part = (float*)d_ws;
    float*        att  = (float*)d_ws + ATT_FOFF;
    unsigned int* cnt  = (unsigned int*)((char*)d_ws + CNT_BYTE_OFF);
    unsigned int* flag = cnt + BATCHES;

    // Zero the 16+16 sync words (graph-capture-legal async memset).
    hipMemsetAsync(cnt, 0, SYNC_BYTES, stream);

    fusion_fused_kernel<<<NB, T, 0, stream>>>(
        gray, green, rgb, conv_w, conv_b, part, att, cnt, flag, out);
}

// Round 9
// 576.443 us; speedup vs baseline: 2.9384x; 2.9384x over previous
//
#include <hip/hip_runtime.h>
#include <math.h>

// Problem dims: B=16, C=256, H=W=128
#define BATCHES       16
#define HW            (128 * 128)          // 16384 floats per channel
#define VEC_PER_BATCH (1 << 20)            // float4 per (input,batch)
#define T             256                  // threads per block
#define NB            512                  // persistent blocks; co-resident always:
                                           // VGPR<=256 (launch_bounds) -> >=2 blk/CU
#define VEC_PER_BLK   (VEC_PER_BATCH / NB) // 2048 float4 per input per block
#define K4            (VEC_PER_BLK / T)    // 8 float4 per thread per input
#define NMID          8
#define BLKS_PER_MID  (NB / NMID)          // 64

// ws layout (bytes):
//   part[16][3][512] floats @ 0        (98304 B)   -- block partials
//   att [16][3]      floats @ 98304    (192 B)
//   sync region      @ 102400, memset each call:
//     mid [16][8]  : 102400 + (p*8+m)*64     (8192 B, one 64B line each)
//     root[16]     : 110592 + p*64           (1024 B)
//     flag[16]     : 111616 + p*64           (1024 B)
#define PART_OFF_F   0
#define ATT_OFF_F    (BATCHES * 3 * NB)        // 24576 floats
#define SYNC_OFF_B   102400
#define MID_OFF_B    102400
#define ROOT_OFF_B   110592
#define FLAG_OFF_B   111616
#define SYNC_BYTES   10240

typedef float f32x4 __attribute__((ext_vector_type(4)));

#define LD_RLX(p)   __hip_atomic_load((p), __ATOMIC_RELAXED, __HIP_MEMORY_SCOPE_AGENT)
#define LD_ACQ(p)   __hip_atomic_load((p), __ATOMIC_ACQUIRE, __HIP_MEMORY_SCOPE_AGENT)
#define ST_RLX(p,v) __hip_atomic_store((p), (v), __ATOMIC_RELAXED, __HIP_MEMORY_SCOPE_AGENT)
#define ST_REL(p,v) __hip_atomic_store((p), (v), __ATOMIC_RELEASE, __HIP_MEMORY_SCOPE_AGENT)
#define FAA_AR(p,v) __hip_atomic_fetch_add((p), (v), __ATOMIC_ACQ_REL, __HIP_MEMORY_SCOPE_AGENT)

__global__ __launch_bounds__(T, 2) void fusion_fused_kernel(
    const f32x4* __restrict__ gray,
    const f32x4* __restrict__ green,
    const f32x4* __restrict__ rgb,
    const float* __restrict__ conv_w,
    const float* __restrict__ conv_b,
    float* __restrict__ part,           // [16][3][NB]
    float* __restrict__ att,            // [16][3]
    unsigned int* __restrict__ mid,     // [16][8], stride 16 uints (64B)
    unsigned int* __restrict__ root,    // [16],    stride 16 uints
    unsigned int* __restrict__ flag,    // [16],    stride 16 uints
    f32x4* __restrict__ out)
{
    const int blk  = (int)blockIdx.x;
    const int t    = (int)threadIdx.x;
    const int lane = t & 63;
    const int wid  = t >> 6;

    // block = 2048 float4 = 8192 floats = half a channel -> uniform weight
    const float w    = conv_w[blk >> 1];
    const float bias = conv_b[0];

    __shared__ float red[3][T / 64];
    __shared__ float satt[3];

    f32x4 Ag[K4], An[K4], Ar[K4], Bg[K4], Bn[K4], Br[K4];

    auto baseof = [&](int p) {
        return (size_t)p * VEC_PER_BATCH + (size_t)blk * VEC_PER_BLK + (size_t)t;
    };

    auto load_into = [&](f32x4 (&g)[K4], f32x4 (&n)[K4], f32x4 (&r)[K4], int p) {
        const size_t base = baseof(p);
        #pragma unroll
        for (int k = 0; k < K4; ++k) g[k] = gray [base + (size_t)(k * T)];
        #pragma unroll
        for (int k = 0; k < K4; ++k) n[k] = green[base + (size_t)(k * T)];
        #pragma unroll
        for (int k = 0; k < K4; ++k) r[k] = rgb  [base + (size_t)(k * T)];
    };

    // Block-reduce sums of (g,n,r), publish part[p][*][blk], hierarchical arrive.
    auto publish = [&](f32x4 (&g)[K4], f32x4 (&n)[K4], f32x4 (&r)[K4], int p) {
        float sg = 0.f, sn = 0.f, sr = 0.f;
        #pragma unroll
        for (int k = 0; k < K4; ++k) {
            sg += (g[k].x + g[k].y) + (g[k].z + g[k].w);
            sn += (n[k].x + n[k].y) + (n[k].z + n[k].w);
            sr += (r[k].x + r[k].y) + (r[k].z + r[k].w);
        }
        #pragma unroll
        for (int off = 32; off > 0; off >>= 1) {
            sg += __shfl_down(sg, off, 64);
            sn += __shfl_down(sn, off, 64);
            sr += __shfl_down(sr, off, 64);
        }
        if (lane == 0) { red[0][wid] = sg; red[1][wid] = sn; red[2][wid] = sr; }
        __syncthreads();
        if (t == 0) {
            float* P = part + (size_t)p * 3 * NB;
            ST_RLX(&P[0 * NB + blk], ((red[0][0] + red[0][1]) + (red[0][2] + red[0][3])) * w);
            ST_RLX(&P[1 * NB + blk], ((red[1][0] + red[1][1]) + (red[1][2] + red[1][3])) * w);
            ST_RLX(&P[2 * NB + blk], ((red[2][0] + red[2][1]) + (red[2][2] + red[2][3])) * w);
            unsigned prev = FAA_AR(&mid[(p * NMID + (blk / BLKS_PER_MID)) * 16], 1u);
            if (prev == BLKS_PER_MID - 1)
                FAA_AR(&root[p * 16], 1u);
        }
        __syncthreads();
    };

    // Leader block for phase p: wait tree full, fold 512x3 partials -> att, flag.
    auto fold = [&](int p) {
        if (t == 0) {
            while (LD_RLX(&root[p * 16]) < NMID) __builtin_amdgcn_s_sleep(1);
            (void)LD_ACQ(&root[p * 16]);
        }
        __syncthreads();
        #pragma unroll
        for (int i = 0; i < 3; ++i) {
            const float* Pi = part + ((size_t)p * 3 + i) * NB;
            float v = LD_RLX(&Pi[t]) + LD_RLX(&Pi[t + 256]);
            #pragma unroll
            for (int off = 32; off > 0; off >>= 1) v += __shfl_down(v, off, 64);
            if (lane == 0) red[i][wid] = v;
        }
        __syncthreads();
        if (t == 0) {
            #pragma unroll
            for (int i = 0; i < 3; ++i) {
                float tot = (red[i][0] + red[i][1]) + (red[i][2] + red[i][3]);
                float logit = tot * (1.0f / (float)HW) + bias;
                ST_RLX(&att[p * 3 + i], 1.0f / (1.0f + expf(-logit)));
            }
            ST_REL(&flag[p * 16], 1u);
        }
    };

    auto fetch_att = [&](int p, float& a0, float& a1, float& a2) {
        if (t == 0) {
            while (LD_RLX(&flag[p * 16]) == 0u) __builtin_amdgcn_s_sleep(1);
            (void)LD_ACQ(&flag[p * 16]);
            satt[0] = LD_RLX(&att[p * 3 + 0]);
            satt[1] = LD_RLX(&att[p * 3 + 1]);
            satt[2] = LD_RLX(&att[p * 3 + 2]);
        }
        __syncthreads();
        a0 = satt[0]; a1 = satt[1]; a2 = satt[2];
    };

    auto apply = [&](f32x4 (&g)[K4], f32x4 (&n)[K4], f32x4 (&r)[K4],
                     int p, float a0, float a1, float a2) {
        const size_t base = baseof(p);
        #pragma unroll
        for (int k = 0; k < K4; ++k) {
            f32x4 o = g[k] * a0 + (n[k] * a1 + r[k] * a2) * 10.0f;
            __builtin_nontemporal_store(o, &out[base + (size_t)(k * T)]);
        }
    };

    // ---- preamble: batch 0 into A, publish its sums ----
    load_into(Ag, An, Ar, 0);
    publish(Ag, An, Ar, 0);

    // ---- steady state: leg p applies batch p (from A) and loads/publishes p+1 (B) ----
    #pragma unroll 1
    for (int i = 0; i < BATCHES / 2; ++i) {
        {   // even leg: current = A
            const int p = 2 * i;
            if (p < BATCHES - 1) load_into(Bg, Bn, Br, p + 1);
            if (blk == p) fold(p);
            float a0, a1, a2; fetch_att(p, a0, a1, a2);
            apply(Ag, An, Ar, p, a0, a1, a2);
            if (p < BATCHES - 1) publish(Bg, Bn, Br, p + 1);
        }
        {   // odd leg: current = B
            const int p = 2 * i + 1;
            if (p < BATCHES - 1) load_into(Ag, An, Ar, p + 1);
            if (blk == p) fold(p);
            float a0, a1, a2; fetch_att(p, a0, a1, a2);
            apply(Bg, Bn, Br, p, a0, a1, a2);
            if (p < BATCHES - 1) publish(Ag, An, Ar, p + 1);
        }
    }
}

extern "C" void kernel_launch(void* const* d_in, const int* in_sizes, int n_in,
                              void* d_out, int out_size, void* d_ws, size_t ws_size,
                              hipStream_t stream) {
    const f32x4* gray   = (const f32x4*)d_in[0];
    const f32x4* green  = (const f32x4*)d_in[1];
    const f32x4* rgb    = (const f32x4*)d_in[2];
    const float* conv_w = (const float*)d_in[3];
    const float* conv_b = (const float*)d_in[4];
    f32x4* out = (f32x4*)d_out;

    float*        part = (float*)d_ws;
    float*        att  = (float*)d_ws + ATT_OFF_F;
    unsigned int* mid  = (unsigned int*)((char*)d_ws + MID_OFF_B);
    unsigned int* root = (unsigned int*)((char*)d_ws + ROOT_OFF_B);
    unsigned int* flag = (unsigned int*)((char*)d_ws + FLAG_OFF_B);

    // Zero the padded sync counters (graph-capture-legal async memset).
    hipMemsetAsync((char*)d_ws + SYNC_OFF_B, 0, SYNC_BYTES, stream);

    fusion_fused_kernel<<<NB, T, 0, stream>>>(
        gray, green, rgb, conv_w, conv_b, part, att, mid, root, flag, out);
}